// Round 1
// baseline (41.538 us; speedup 1.0000x reference)
//
#include <hip/hip_runtime.h>
#include <hip/hip_fp16.h>
#include <math.h>

#define TSTEPS 23
#define NTOK 66

// ws layout (float offsets)
#define WS_Z  0            // [64][64] sigmoid score LUT
#define WS_QP 4096         // [66][64] embed@rw1_top + rb1
#define WS_R8 8320         // [66][64] 0.125 * embed@rw1_bot
// total 12544 floats = 50176 bytes

__global__ __launch_bounds__(256) void sm_precompute(
    const float* __restrict__ embed,
    const float* __restrict__ gw1,
    const float* __restrict__ gb1,
    const float* __restrict__ gw2,
    const float* __restrict__ gb2,
    const float* __restrict__ rw1,
    const float* __restrict__ rb1,
    float* __restrict__ ws)
{
    const int tid = threadIdx.x;
    const int blk = blockIdx.x;
    if (blk < 16) {
        // Z table rows c in [blk*4, blk*4+4)
        __shared__ float v[64 * 32];
        __shared__ float u[4 * 32];
        for (int idx = tid; idx < 64 * 32; idx += 256) {
            const int s = idx >> 5, j = idx & 31;
            float acc = 0.f;
            const float* er = embed + s * 64;
            for (int k = 0; k < 64; ++k)
                acc = fmaf(er[k], gw1[(64 + k) * 32 + j], acc);
            v[idx] = acc;
        }
        if (tid < 128) {
            const int cc = tid >> 5, j = tid & 31;
            const int c = blk * 4 + cc;
            float acc = 0.f;
            const float* er = embed + c * 64;
            for (int k = 0; k < 64; ++k)
                acc = fmaf(er[k], gw1[k * 32 + j], acc);
            u[tid] = acc;
        }
        __syncthreads();
        const int cc = tid >> 6, s = tid & 63;
        const int c = blk * 4 + cc;
        double z = (double)gb2[0];
        for (int j = 0; j < 32; ++j) {
            const double a = (double)u[cc * 32 + j] + (double)v[s * 32 + j] + (double)gb1[j];
            if (a > 0.0) z += a * (double)gw2[j];
        }
        ws[WS_Z + c * 64 + s] = (float)(1.0 / (1.0 + exp(-z)));
    } else if (blk == 16) {
        for (int idx = tid; idx < NTOK * 64; idx += 256) {
            const int t = idx >> 6, j = idx & 63;
            float acc = rb1[j];
            const float* er = embed + t * 64;
            for (int k = 0; k < 64; ++k)
                acc = fmaf(er[k], rw1[k * 64 + j], acc);
            ws[WS_QP + idx] = acc;
        }
    } else {
        for (int idx = tid; idx < NTOK * 64; idx += 256) {
            const int t = idx >> 6, j = idx & 63;
            float acc = 0.f;
            const float* er = embed + t * 64;
            for (int k = 0; k < 64; ++k)
                acc = fmaf(er[k], rw1[(64 + k) * 64 + j], acc);
            ws[WS_R8 + idx] = 0.125f * acc;
        }
    }
}

#define ROWS 64
#define BT 256

__global__ __launch_bounds__(BT) void sm_main(
    const int* __restrict__ seqs,
    const int* __restrict__ qtok,
    const float* __restrict__ rw2,
    const float* __restrict__ rb2,
    const float* __restrict__ ws,
    float* __restrict__ out)
{
    __shared__ float sZ[64 * 65];          // padded: bank = (c + s) % 32
    __shared__ float sR8[64 * 66];         // transposed [j][tok], stride 66
    __shared__ float sW2[64 * 64];         // rw2 as-is (broadcast reads)
    __shared__ __half sH[ROWS * 66];       // h per row, padded stride 66
    __shared__ unsigned sTokPk[ROWS * 6];  // 24 tokens/row packed as bytes
    __shared__ uint2 sSlots[ROWS];

    const int tid = threadIdx.x;
    const int base = blockIdx.x * ROWS;

    // --- stage tables into LDS ---
    for (int idx = tid; idx < 64 * 64; idx += BT)
        sZ[(idx >> 6) * 65 + (idx & 63)] = ws[WS_Z + idx];
    {
        const float4* w4 = (const float4*)rw2;
        float4* s4 = (float4*)sW2;
        for (int idx = tid; idx < 64 * 16; idx += BT)
            s4[idx] = w4[idx];
    }
    for (int idx = tid; idx < 64 * 64; idx += BT) {
        const int t = idx >> 6, j = idx & 63;
        sR8[j * 66 + t] = ws[WS_R8 + idx];
    }
    {
        const int4* sq = (const int4*)(seqs + base * 24);
        for (int g = tid; g < ROWS * 6; g += BT) {
            const int4 w = sq[g];
            sTokPk[g] = (unsigned)w.x | ((unsigned)w.y << 8) |
                        ((unsigned)w.z << 16) | ((unsigned)w.w << 24);
        }
    }
    __syncthreads();

    // --- scan: one thread per row (wave 0) ---
    if (tid < ROWS) {
        const unsigned char* tk = ((const unsigned char*)sTokPk) + tid * 24;
        unsigned lo = sTokPk[tid * 6 + 0];   // slots 0..3 = tokens t=0..3
        unsigned hi = sTokPk[tid * 6 + 1];   // slots 4..7 = tokens t=4..7
        #pragma unroll
        for (int t = 8; t < TSTEPS; ++t) {
            const int c = tk[t];
            const float* zr = sZ + c * 65;
            float b = zr[lo & 63]; int am = 0; float z;
            z = zr[(lo >> 8) & 63];  if (z > b) { b = z; am = 1; }
            z = zr[(lo >> 16) & 63]; if (z > b) { b = z; am = 2; }
            z = zr[lo >> 24];        if (z > b) { b = z; am = 3; }
            z = zr[hi & 63];         if (z > b) { b = z; am = 4; }
            z = zr[(hi >> 8) & 63];  if (z > b) { b = z; am = 5; }
            z = zr[(hi >> 16) & 63]; if (z > b) { b = z; am = 6; }
            z = zr[hi >> 24];        if (z > b) { b = z; am = 7; }
            const unsigned cb = (unsigned)c;
            if (am < 4) {
                const int sh = am * 8;
                lo = (lo & ~(255u << sh)) | (cb << sh);
            } else {
                const int sh = am * 8 - 32;
                hi = (hi & ~(255u << sh)) | (cb << sh);
            }
        }
        sSlots[tid] = make_uint2(lo, hi);
    }
    __syncthreads();

    // --- h phase: thread (q, r) computes h[j] for j in [q*16, q*16+16) ---
    const int r = tid & (ROWS - 1);
    const int q = tid >> 6;
    {
        const uint2 sl = sSlots[r];
        const int ts0 = sl.x & 63, ts1 = (sl.x >> 8) & 63, ts2 = (sl.x >> 16) & 63, ts3 = sl.x >> 24;
        const int ts4 = sl.y & 63, ts5 = (sl.y >> 8) & 63, ts6 = (sl.y >> 16) & 63, ts7 = sl.y >> 24;
        const int qt = qtok[base + r];
        const float4* qpv = (const float4*)(ws + WS_QP + qt * 64 + q * 16);
        float hj[16];
        {
            const float4 a0 = qpv[0], a1 = qpv[1], a2 = qpv[2], a3 = qpv[3];
            hj[0] = a0.x; hj[1] = a0.y; hj[2] = a0.z; hj[3] = a0.w;
            hj[4] = a1.x; hj[5] = a1.y; hj[6] = a1.z; hj[7] = a1.w;
            hj[8] = a2.x; hj[9] = a2.y; hj[10] = a2.z; hj[11] = a2.w;
            hj[12] = a3.x; hj[13] = a3.y; hj[14] = a3.z; hj[15] = a3.w;
        }
        const float* rbase = sR8 + (q * 16) * 66;
        #pragma unroll
        for (int jj = 0; jj < 16; ++jj) {
            const float* rr = rbase + jj * 66;
            hj[jj] += rr[ts0]; hj[jj] += rr[ts1];
            hj[jj] += rr[ts2]; hj[jj] += rr[ts3];
            hj[jj] += rr[ts4]; hj[jj] += rr[ts5];
            hj[jj] += rr[ts6]; hj[jj] += rr[ts7];
        }
        __half* hw = sH + r * 66 + q * 16;
        #pragma unroll
        for (int jj = 0; jj < 16; ++jj)
            hw[jj] = __float2half(hj[jj] > 0.f ? hj[jj] : 0.f);
    }
    __syncthreads();

    // --- readout dot: logits[i] = sum_j h[j]*rw2[j][i] + rb2[i] ---
    float4 ac0, ac1, ac2, ac3;
    {
        const float4* rb = (const float4*)(rb2 + q * 16);
        ac0 = rb[0]; ac1 = rb[1]; ac2 = rb[2]; ac3 = rb[3];
    }
    const float4* w2v = (const float4*)sW2;
    const __half* hrow = sH + r * 66;
    #pragma unroll 4
    for (int j = 0; j < 64; ++j) {
        const float hv = __half2float(hrow[j]);
        const float4 w0 = w2v[j * 16 + q * 4 + 0];
        const float4 w1 = w2v[j * 16 + q * 4 + 1];
        const float4 w2_ = w2v[j * 16 + q * 4 + 2];
        const float4 w3 = w2v[j * 16 + q * 4 + 3];
        ac0.x = fmaf(hv, w0.x, ac0.x); ac0.y = fmaf(hv, w0.y, ac0.y);
        ac0.z = fmaf(hv, w0.z, ac0.z); ac0.w = fmaf(hv, w0.w, ac0.w);
        ac1.x = fmaf(hv, w1.x, ac1.x); ac1.y = fmaf(hv, w1.y, ac1.y);
        ac1.z = fmaf(hv, w1.z, ac1.z); ac1.w = fmaf(hv, w1.w, ac1.w);
        ac2.x = fmaf(hv, w2_.x, ac2.x); ac2.y = fmaf(hv, w2_.y, ac2.y);
        ac2.z = fmaf(hv, w2_.z, ac2.z); ac2.w = fmaf(hv, w2_.w, ac2.w);
        ac3.x = fmaf(hv, w3.x, ac3.x); ac3.y = fmaf(hv, w3.y, ac3.y);
        ac3.z = fmaf(hv, w3.z, ac3.z); ac3.w = fmaf(hv, w3.w, ac3.w);
    }
    float4* op = (float4*)(out + (size_t)(base + r) * 64 + q * 16);
    op[0] = ac0; op[1] = ac1; op[2] = ac2; op[3] = ac3;
}

extern "C" void kernel_launch(void* const* d_in, const int* in_sizes, int n_in,
                              void* d_out, int out_size, void* d_ws, size_t ws_size,
                              hipStream_t stream)
{
    const int* seqs    = (const int*)d_in[0];
    const int* qtok    = (const int*)d_in[1];
    const float* embed = (const float*)d_in[2];
    const float* gw1   = (const float*)d_in[3];
    const float* gb1   = (const float*)d_in[4];
    const float* gw2   = (const float*)d_in[5];
    const float* gb2   = (const float*)d_in[6];
    const float* rw1   = (const float*)d_in[7];
    const float* rb1   = (const float*)d_in[8];
    const float* rw2   = (const float*)d_in[9];
    const float* rb2   = (const float*)d_in[10];
    float* ws  = (float*)d_ws;
    float* out = (float*)d_out;
    const int B = in_sizes[1];

    sm_precompute<<<18, 256, 0, stream>>>(embed, gw1, gb1, gw2, gb2, rw1, rb1, ws);
    sm_main<<<B / ROWS, BT, 0, stream>>>(seqs, qtok, rw2, rb2, ws, out);
}